// Round 9
// baseline (2046.287 us; speedup 1.0000x reference)
//
#include <hip/hip_runtime.h>

typedef float f32x4 __attribute__((ext_vector_type(4)));
typedef __bf16 bf16x8 __attribute__((ext_vector_type(8)));
typedef unsigned short u16x8 __attribute__((ext_vector_type(8)));
typedef unsigned short u16x4 __attribute__((ext_vector_type(4)));

static __device__ __forceinline__ unsigned short f2bf(float f) {
  unsigned int x = __builtin_bit_cast(unsigned int, f);
  x += 0x7FFFu + ((x >> 16) & 1u);
  return (unsigned short)(x >> 16);
}
static __device__ __forceinline__ float bf2f(unsigned short h) {
  unsigned int x = ((unsigned int)h) << 16;
  return __builtin_bit_cast(float, x);
}

static __device__ __forceinline__ void gload_lds16(const unsigned short* g,
                                                   unsigned short* l) {
  __builtin_amdgcn_global_load_lds(
      (const __attribute__((address_space(1))) void*)g,
      (__attribute__((address_space(3))) void*)l, 16, 0, 0);
}

// ---------------- f32 -> bf16 elementwise (vectorized) ----------------
__global__ __launch_bounds__(256) void k_f32_to_bf16(
    const float* __restrict__ in, unsigned short* __restrict__ out, int n4) {
  int i = blockIdx.x * 256 + threadIdx.x;
  if (i >= n4) return;
  float4 v = reinterpret_cast<const float4*>(in)[i];
  u16x4 o = {f2bf(v.x), f2bf(v.y), f2bf(v.z), f2bf(v.w)};
  reinterpret_cast<u16x4*>(out)[i] = o;
}

// ------- transpose+convert into grouped B^T layout -------
__global__ __launch_bounds__(256) void k_transpose_w(
    const float* __restrict__ in, unsigned short* __restrict__ out, int RG) {
  __shared__ float tile[32][33];
  const int D = 768;
  int z = blockIdx.z;
  int j = z % RG, grp = z / RG;
  const float* A = in + (size_t)z * D * D;
  const size_t ld = (size_t)RG * D;
  unsigned short* O = out + (size_t)grp * D * ld + (size_t)j * D;
  int nt = blockIdx.x * 32, kt = blockIdx.y * 32;
  int tx = threadIdx.x, ty = threadIdx.y;
#pragma unroll
  for (int i = 0; i < 4; ++i)
    tile[ty + i * 8][tx] = A[(size_t)(kt + ty + i * 8) * D + nt + tx];
  __syncthreads();
#pragma unroll
  for (int i = 0; i < 4; ++i)
    O[(size_t)(nt + ty + i * 8) * ld + kt + tx] = f2bf(tile[tx][ty + i * 8]);
}

// ---------------- edge sort by (rel, dst) ----------------
__global__ __launch_bounds__(256) void k_hist(const int* __restrict__ dst,
                                              const int* __restrict__ rel,
                                              int* __restrict__ cnt, int E, int NV) {
  int e = blockIdx.x * 256 + threadIdx.x;
  if (e < E) atomicAdd(&cnt[rel[e] * NV + dst[e]], 1);
}

__global__ __launch_bounds__(256) void k_part(const int* __restrict__ cnt,
                                              int* __restrict__ bsum, int n) {
  __shared__ int wsums[4];
  int blk = blockIdx.x, tid = threadIdx.x;
  int base = blk * 1024 + tid * 4;
  int s = 0;
#pragma unroll
  for (int j = 0; j < 4; ++j) {
    int i = base + j;
    if (i < n) s += cnt[i];
  }
#pragma unroll
  for (int d = 1; d < 64; d <<= 1) s += __shfl_xor(s, d, 64);
  if ((tid & 63) == 0) wsums[tid >> 6] = s;
  __syncthreads();
  if (tid == 0) bsum[blk] = wsums[0] + wsums[1] + wsums[2] + wsums[3];
}

__global__ __launch_bounds__(1024) void k_scan_b(const int* __restrict__ bsum,
                                                 int* __restrict__ bscan, int nb,
                                                 int* __restrict__ off_total) {
  __shared__ int wpre[16];
  int tid = threadIdx.x, lane = tid & 63, w = tid >> 6;
  int v = (tid < nb) ? bsum[tid] : 0;
  int inc = v;
#pragma unroll
  for (int d = 1; d < 64; d <<= 1) {
    int t = __shfl_up(inc, d, 64);
    if (lane >= d) inc += t;
  }
  if (lane == 63) wpre[w] = inc;
  __syncthreads();
  if (w == 0) {
    int vv = (lane < 16) ? wpre[lane] : 0;
    int p = vv;
#pragma unroll
    for (int d = 1; d < 16; d <<= 1) {
      int t = __shfl_up(p, d, 64);
      if (lane >= d) p += t;
    }
    if (lane < 16) wpre[lane] = p - vv;
  }
  __syncthreads();
  if (tid < nb) bscan[tid] = wpre[w] + inc - v;
  if (tid == 1023) *off_total = wpre[15] + inc;
}

__global__ __launch_bounds__(256) void k_scan_f(const int* __restrict__ cnt,
                                                const int* __restrict__ bscan,
                                                int* __restrict__ off, int n) {
  __shared__ int wpre[4];
  int blk = blockIdx.x, tid = threadIdx.x, lane = tid & 63, w = tid >> 6;
  int base = blk * 1024 + tid * 4;
  int v[4];
  int s = 0;
#pragma unroll
  for (int j = 0; j < 4; ++j) {
    int i = base + j;
    v[j] = (i < n) ? cnt[i] : 0;
    s += v[j];
  }
  int inc = s;
#pragma unroll
  for (int d = 1; d < 64; d <<= 1) {
    int t = __shfl_up(inc, d, 64);
    if (lane >= d) inc += t;
  }
  if (lane == 63) wpre[w] = inc;
  __syncthreads();
  int wb = 0;
  for (int j = 0; j < w; ++j) wb += wpre[j];
  int run = bscan[blk] + wb + (inc - s);
#pragma unroll
  for (int j = 0; j < 4; ++j) {
    int i = base + j;
    if (i < n) off[i] = run;
    run += v[j];
  }
}

__global__ __launch_bounds__(256) void k_bucket(
    const int* __restrict__ src, const int* __restrict__ dst,
    const int* __restrict__ rel, const float* __restrict__ norm,
    const int* __restrict__ off, int* __restrict__ fill,
    int* __restrict__ spack, float* __restrict__ snorm, int E, int NV) {
  int e = blockIdx.x * 256 + threadIdx.x;
  if (e >= E) return;
  int key = rel[e] * NV + dst[e];
  int slot = off[key] + atomicAdd(&fill[key], 1);
  spack[slot] = src[e];
  snorm[slot] = norm[e];
}

// ------- gather-aggregate into K-concat A slices -------
__global__ __launch_bounds__(256) void k_gather(
    const unsigned short* __restrict__ h, const int* __restrict__ off,
    const int* __restrict__ spack, const float* __restrict__ snorm,
    unsigned short* __restrict__ Acat, int NV, int r0, int r1, int ld) {
  int v = (blockIdx.x * 256 + threadIdx.x) >> 6;
  int lane = threadIdx.x & 63;
  int col = lane * 4;
  for (int r = r0; r < r1; ++r) {
    float a[12];
#pragma unroll
    for (int j = 0; j < 12; ++j) a[j] = 0.f;
    if (v < NV) {
      int beg = off[r * NV + v], end = off[r * NV + v + 1];
      for (int p = beg; p < end; ++p) {
        const unsigned short* row = h + (size_t)spack[p] * 768 + col;
        float nm = snorm[p];
#pragma unroll
        for (int c = 0; c < 3; ++c) {
          u16x4 vv = *reinterpret_cast<const u16x4*>(row + c * 256);
#pragma unroll
          for (int j = 0; j < 4; ++j) a[c * 4 + j] += nm * bf2f(vv[j]);
        }
      }
    }
    unsigned short* orow = Acat + (size_t)v * ld + (size_t)(r - r0) * 768 + col;
#pragma unroll
    for (int c = 0; c < 3; ++c) {
      u16x4 o = {f2bf(a[c * 4 + 0]), f2bf(a[c * 4 + 1]),
                 f2bf(a[c * 4 + 2]), f2bf(a[c * 4 + 3])};
      *reinterpret_cast<u16x4*>(orow + c * 256) = o;
    }
  }
}

// ---------------- target sort by relation (8 buckets) ----------------
__global__ __launch_bounds__(256) void k_thist(
    const int* __restrict__ pr, const int* __restrict__ nr,
    int* __restrict__ tcnt, int T) {
  int t = blockIdx.x * 256 + threadIdx.x;
  if (t >= 2 * T) return;
  int r = (t < T) ? pr[t] : nr[t - T];
  atomicAdd(&tcnt[r], 1);
}

// single-thread: padded offsets + per-tile relation map (tiny: R + ntiles iters)
__global__ void k_tscan(const int* __restrict__ tcnt, int* __restrict__ tpo,
                        int* __restrict__ btile, int R, int ntiles) {
  int run = 0;
  for (int r = 0; r < R; ++r) {
    tpo[r] = run;
    run += (tcnt[r] + 255) & ~255;
  }
  tpo[R] = run;
  for (int mt = 0; mt < ntiles; ++mt) {
    int base = mt * 256;
    int b = -1;
    if (base < run)
      for (int r = 0; r < R; ++r)
        if (base >= tpo[r] && base < tpo[r + 1]) { b = r; break; }
    btile[mt] = b;
  }
}

__global__ __launch_bounds__(256) void k_tbucket(
    const int* __restrict__ ps, const int* __restrict__ pr, const int* __restrict__ pd,
    const int* __restrict__ ns, const int* __restrict__ nr, const int* __restrict__ nd,
    const int* __restrict__ tpo, int* __restrict__ tfill,
    int* __restrict__ sidx, int* __restrict__ oidx, int* __restrict__ tmap, int T) {
  int t = blockIdx.x * 256 + threadIdx.x;
  if (t >= 2 * T) return;
  int s, r, o;
  if (t < T) { s = ps[t]; r = pr[t]; o = pd[t]; }
  else       { s = ns[t - T]; r = nr[t - T]; o = nd[t - T]; }
  int slot = tpo[r] + atomicAdd(&tfill[r], 1);
  sidx[slot] = s;
  oidx[slot] = o;
  tmap[slot] = t;
}

// ================= shared GEMM pieces (256x256 tile, BK=64, 8 waves) =========
// 16B-chunk XOR swizzle chunk^=(row&7) on pre-swizzled global source; matching
// XOR on ds_read. A/B rows padded to multiples of 256.
// EPI: 0 = bf16 C; 1 = bf16 relu(acc + C0_f32); 2 = f32 C; 3 = f32 acc + C0.
#define STAGE_A(BUF, HALF, TT)                                                   \
  do {                                                                           \
    const unsigned short* _s =                                                   \
        A + (size_t)(m0 + (HALF) * 128 + srow) * K + (size_t)(TT) * 64 + gcol;   \
    gload_lds16(_s, &As[BUF][HALF][w << 3][0]);                                  \
    gload_lds16(_s + (size_t)64 * K, &As[BUF][HALF][64 + (w << 3)][0]);          \
  } while (0)
#define STAGE_B(BUF, HALF, TT)                                                   \
  do {                                                                           \
    const unsigned short* _s =                                                   \
        B + (size_t)(n0 + (HALF) * 128 + srow) * K + (size_t)(TT) * 64 + gcol;   \
    gload_lds16(_s, &Bs[BUF][HALF][w << 3][0]);                                  \
    gload_lds16(_s + (size_t)64 * K, &Bs[BUF][HALF][64 + (w << 3)][0]);          \
  } while (0)
#define GEMM_PRE()                                                               \
  const int tid = threadIdx.x;                                                   \
  const int lane = tid & 63;                                                     \
  const int w = tid >> 6;                                                        \
  const int wr = w >> 2;                                                         \
  const int wc = w & 3;                                                          \
  const int lr = lane & 15, lg = lane >> 4;                                      \
  int bid = blockIdx.x;                                                          \
  const int per = 8 * NT;                                                        \
  int grp = bid / per, rem = bid % per;                                          \
  int mstart = grp * 8;                                                          \
  int gsz = MT - mstart;                                                         \
  if (gsz > 8) gsz = 8;                                                          \
  const int mt = mstart + rem % gsz;                                             \
  const int ntile = rem / gsz;                                                   \
  const int m0 = mt * 256, n0 = ntile * 256;                                     \
  const int srow = tid >> 3;                                                     \
  const int gcol = (((tid & 7) ^ (tid >> 3)) & 7) * 8;                           \
  const int nk = K >> 6;
#define R_BV6(BUF)                                                               \
  _Pragma("unroll") for (int nb = 0; nb < 2; ++nb)                               \
  _Pragma("unroll") for (int j = 0; j < 2; ++j)                                  \
  _Pragma("unroll") for (int kk = 0; kk < 2; ++kk)                               \
      bv[nb][j][kk] = *reinterpret_cast<const bf16x8*>(                          \
          &Bs[BUF][nb][wc * 32 + j * 16 + lr][((lg + 4 * kk) ^ (lr & 7)) * 8]);
#define R_AF6(BUF, HALF)                                                         \
  _Pragma("unroll") for (int i = 0; i < 4; ++i)                                  \
  _Pragma("unroll") for (int kk = 0; kk < 2; ++kk)                               \
      af[i][kk] = *reinterpret_cast<const bf16x8*>(                              \
          &As[BUF][HALF][wr * 64 + i * 16 + lr][((lg + 4 * kk) ^ (lr & 7)) * 8]);
// r6 2-phase main loop body (STAGEA_MACRO lets the score kernel use indirect A)
#define GEMM_LOOP(STAGEA_MACRO)                                                  \
  bf16x8 af[4][2], bv[2][2][2];                                                  \
  for (int t = 0; t < nk; ++t) {                                                 \
    const int buf = t & 1;                                                       \
    if (t + 1 < nk)                                                              \
      asm volatile("s_waitcnt vmcnt(4)" ::: "memory");                           \
    else                                                                         \
      asm volatile("s_waitcnt vmcnt(0)" ::: "memory");                           \
    __builtin_amdgcn_s_barrier();                                                \
    asm volatile("" ::: "memory");                                               \
    R_AF6(buf, 0);                                                               \
    R_BV6(buf);                                                                  \
    if (t + 1 < nk) {                                                            \
      STAGEA_MACRO(buf ^ 1, 1, t + 1);                                           \
      STAGE_B(buf ^ 1, 0, t + 1);                                                \
    }                                                                            \
    __builtin_amdgcn_s_setprio(1);                                               \
    _Pragma("unroll") for (int i = 0; i < 4; ++i)                                \
    _Pragma("unroll") for (int nb = 0; nb < 2; ++nb)                             \
    _Pragma("unroll") for (int j = 0; j < 2; ++j)                                \
    _Pragma("unroll") for (int kk = 0; kk < 2; ++kk)                             \
        acc[0][nb][i][j] = __builtin_amdgcn_mfma_f32_16x16x32_bf16(              \
            af[i][kk], bv[nb][j][kk], acc[0][nb][i][j], 0, 0, 0);                \
    __builtin_amdgcn_s_setprio(0);                                               \
    asm volatile("" ::: "memory");                                               \
    __builtin_amdgcn_s_barrier();                                                \
    asm volatile("" ::: "memory");                                               \
    R_AF6(buf, 1);                                                               \
    if (t + 2 < nk) {                                                            \
      STAGEA_MACRO(buf, 0, t + 2);                                               \
      STAGE_B(buf, 1, t + 2);                                                    \
    }                                                                            \
    __builtin_amdgcn_s_setprio(1);                                               \
    _Pragma("unroll") for (int i = 0; i < 4; ++i)                                \
    _Pragma("unroll") for (int nb = 0; nb < 2; ++nb)                             \
    _Pragma("unroll") for (int j = 0; j < 2; ++j)                                \
    _Pragma("unroll") for (int kk = 0; kk < 2; ++kk)                             \
        acc[1][nb][i][j] = __builtin_amdgcn_mfma_f32_16x16x32_bf16(              \
            af[i][kk], bv[nb][j][kk], acc[1][nb][i][j], 0, 0, 0);                \
    __builtin_amdgcn_s_setprio(0);                                               \
  }

// ---------------- k_gemm_tn: round-6 2-phase schedule ----------------
template <int EPI>
__global__ __launch_bounds__(512, 2) void k_gemm_tn(
    const unsigned short* __restrict__ A, const unsigned short* __restrict__ B,
    void* __restrict__ Cp, const float* __restrict__ C0,
    int M, int N, int K, int MT, int NT) {
  __shared__ unsigned short As[2][2][128][64];
  __shared__ unsigned short Bs[2][2][128][64];
  GEMM_PRE();
  f32x4 acc[2][2][4][2] = {};

  STAGE_A(0, 0, 0);
  STAGE_B(0, 1, 0);
  STAGE_A(0, 1, 0);
  STAGE_B(0, 0, 0);
  if (nk > 1) {
    STAGE_A(1, 0, 1);
    STAGE_B(1, 1, 1);
  }
  GEMM_LOOP(STAGE_A);

#pragma unroll
  for (int ma = 0; ma < 2; ++ma)
#pragma unroll
    for (int i = 0; i < 4; ++i)
#pragma unroll
      for (int q = 0; q < 4; ++q) {
        int r = m0 + ma * 128 + wr * 64 + i * 16 + lg * 4 + q;
        if (r >= M) continue;
#pragma unroll
        for (int nb = 0; nb < 2; ++nb)
#pragma unroll
          for (int j = 0; j < 2; ++j) {
            int cn = n0 + nb * 128 + wc * 32 + j * 16 + lr;
            float v = acc[ma][nb][i][j][q];
            size_t idx = (size_t)r * N + cn;
            if (EPI == 0) {
              ((unsigned short*)Cp)[idx] = f2bf(v);
            } else if (EPI == 1) {
              v += C0[idx];
              v = v > 0.f ? v : 0.f;
              ((unsigned short*)Cp)[idx] = f2bf(v);
            } else if (EPI == 2) {
              ((float*)Cp)[idx] = v;
            } else {
              ((float*)Cp)[idx] = v + C0[idx];
            }
          }
      }
}

// ---------------- k_gemm_score: indirect-A batched-B GEMM + fused DistMult dot --
// M-tiles grouped by relation (btile[mt] = r, or -1 = pad tile -> exit).
// A rows gathered via sidx[] through per-lane global_load_lds addresses
// (h is L3-resident). Epilogue: per row, partial = sum_cols acc*o[col],
// 16-lane shfl reduce, one f32 atomicAdd per (row, wave, N-block) into out.
#define STAGE_AI(BUF, HALF, TT)                                                  \
  do {                                                                           \
    gload_lds16(pa##HALF##a + (size_t)(TT) * 64, &As[BUF][HALF][w << 3][0]);     \
    gload_lds16(pa##HALF##b + (size_t)(TT) * 64,                                 \
                &As[BUF][HALF][64 + (w << 3)][0]);                               \
  } while (0)

__global__ __launch_bounds__(512, 2) void k_gemm_score(
    const unsigned short* __restrict__ h, const unsigned short* __restrict__ Bw,
    float* __restrict__ out, const int* __restrict__ sidx,
    const int* __restrict__ oidx, const int* __restrict__ tmap,
    const int* __restrict__ btile, int MT, int NT) {
  const int K = 768;
  __shared__ unsigned short As[2][2][128][64];
  __shared__ unsigned short Bs[2][2][128][64];
  GEMM_PRE();
  const int bt = btile[mt];
  if (bt < 0) return;
  const unsigned short* B = Bw + (size_t)bt * K * K;
  // indirect A row pointers (4 rows per thread)
  const unsigned short* pa0a = h + (size_t)sidx[m0 + srow] * K + gcol;
  const unsigned short* pa0b = h + (size_t)sidx[m0 + 64 + srow] * K + gcol;
  const unsigned short* pa1a = h + (size_t)sidx[m0 + 128 + srow] * K + gcol;
  const unsigned short* pa1b = h + (size_t)sidx[m0 + 192 + srow] * K + gcol;

  f32x4 acc[2][2][4][2] = {};

  STAGE_AI(0, 0, 0);
  STAGE_B(0, 1, 0);
  STAGE_AI(0, 1, 0);
  STAGE_B(0, 0, 0);
  STAGE_AI(1, 0, 1);
  STAGE_B(1, 1, 1);
  GEMM_LOOP(STAGE_AI);

  // fused epilogue: score[t] += dot(row, h[oidx])
#pragma unroll
  for (int ma = 0; ma < 2; ++ma)
#pragma unroll
    for (int i = 0; i < 4; ++i)
#pragma unroll
      for (int q = 0; q < 4; ++q) {
        int slot = m0 + ma * 128 + wr * 64 + i * 16 + lg * 4 + q;
        int t = tmap[slot];
        float p = 0.f;
        if (t >= 0) {
          const unsigned short* orow = h + (size_t)oidx[slot] * K;
#pragma unroll
          for (int nb = 0; nb < 2; ++nb)
#pragma unroll
            for (int j = 0; j < 2; ++j) {
              int cn = n0 + nb * 128 + wc * 32 + j * 16 + lr;
              p += acc[ma][nb][i][j][q] * bf2f(orow[cn]);
            }
        }
#pragma unroll
        for (int d = 1; d < 16; d <<= 1) p += __shfl_xor(p, d, 64);
        if (t >= 0 && lr == 0) unsafeAtomicAdd(&out[t], p);
      }
}

extern "C" void kernel_launch(void* const* d_in, const int* in_sizes, int n_in,
                              void* d_out, int out_size, void* d_ws, size_t ws_size,
                              hipStream_t stream) {
  const float* node_feat = (const float*)d_in[0];
  const float* edge_norm = (const float*)d_in[1];
  const float* W_rel = (const float*)d_in[2];
  const float* W_self = (const float*)d_in[3];
  const float* w_relation = (const float*)d_in[4];
  const int* src = (const int*)d_in[5];
  const int* dst = (const int*)d_in[6];
  const int* rel = (const int*)d_in[7];
  const int* pos_src = (const int*)d_in[8];
  const int* pos_rel = (const int*)d_in[9];
  const int* pos_dst = (const int*)d_in[10];
  const int* neg_src = (const int*)d_in[11];
  const int* neg_rel = (const int*)d_in[12];
  const int* neg_dst = (const int*)d_in[13];

  const int D = 768;
  const int NV = in_sizes[0] / D;
  const int E = in_sizes[1];
  const int L = in_sizes[3] / (D * D);
  const int R = in_sizes[4] / (D * D);
  const int T = in_sizes[8];
  const int Mpad = (NV + 255) & ~255;
  const int RN = R * NV;
  const int NB = (RN + 1023) / 1024;
  const int TB = (2 * T + R * 256 + 255) / 256;  // scoring tile bound
  const int Mbound = TB * 256;

  auto align_up = [](size_t x) { return (x + 255) & ~(size_t)255; };
  size_t sz_wt_rel = align_up((size_t)L * R * D * D * 2);
  size_t sz_wt_self = align_up((size_t)L * D * D * 2);
  size_t sz_wt_score = align_up((size_t)R * D * D * 2);
  size_t sz_h = align_up((size_t)Mpad * D * 2);
  size_t sz_agg = align_up((size_t)Mpad * D * 4);
  size_t sz_cntfill = align_up((size_t)2 * RN * 4);
  size_t sz_off = align_up((size_t)(RN + 8) * 4);
  size_t sz_sp = align_up((size_t)E * 4);
  size_t sz_bs = align_up((size_t)2 * (NB + 8) * 4);
  size_t sz_tix = align_up((size_t)Mbound * 4);
  size_t sz_tsmall = align_up((size_t)(TB + 64) * 4);
  size_t fixed = sz_wt_rel + sz_wt_self + sz_wt_score + sz_h + sz_agg +
                 sz_cntfill + sz_off + 2 * sz_sp + sz_bs + 3 * sz_tix +
                 sz_tsmall;
  int RG = 4;
  while (RG > 1 && fixed + align_up((size_t)Mpad * RG * D * 2) > ws_size) RG >>= 1;
  const int NGRP = R / RG;

  char* wp = (char*)d_ws;
  unsigned short* wt_rel = (unsigned short*)wp; wp += sz_wt_rel;
  unsigned short* wt_self = (unsigned short*)wp; wp += sz_wt_self;
  unsigned short* wt_score = (unsigned short*)wp; wp += sz_wt_score;
  unsigned short* h = (unsigned short*)wp; wp += sz_h;
  float* agg = (float*)wp; wp += sz_agg;
  int* cnt = (int*)wp; int* fill = cnt + RN; wp += sz_cntfill;
  int* off = (int*)wp; wp += sz_off;
  int* spack = (int*)wp; wp += sz_sp;
  float* snorm = (float*)wp; wp += sz_sp;
  int* bsum = (int*)wp; int* bscan = bsum + NB + 4; wp += sz_bs;
  int* sidx = (int*)wp; wp += sz_tix;
  int* oidx = (int*)wp; wp += sz_tix;
  int* tmap = (int*)wp; wp += sz_tix;
  int* btile = (int*)wp;                  // TB ints
  int* tcnt = btile + TB + 8;             // R
  int* tfill = tcnt + R + 8;              // R
  int* tpo = tfill + R + 8;               // R+1
  wp += sz_tsmall;
  unsigned short* Acat = (unsigned short*)wp;

  dim3 tb32(32, 8);
  k_f32_to_bf16<<<(NV * D / 4 + 255) / 256, 256, 0, stream>>>(node_feat, h, NV * D / 4);
  if (Mpad > NV)
    hipMemsetAsync(h + (size_t)NV * D, 0, (size_t)(Mpad - NV) * D * 2, stream);
  k_transpose_w<<<dim3(24, 24, L * R), tb32, 0, stream>>>(W_rel, wt_rel, RG);
  k_transpose_w<<<dim3(24, 24, L), tb32, 0, stream>>>(W_self, wt_self, 1);
  k_transpose_w<<<dim3(24, 24, R), tb32, 0, stream>>>(w_relation, wt_score, 1);

  // edge sort by (rel, dst)
  hipMemsetAsync(cnt, 0, (size_t)2 * RN * 4, stream);
  k_hist<<<(E + 255) / 256, 256, 0, stream>>>(dst, rel, cnt, E, NV);
  k_part<<<NB, 256, 0, stream>>>(cnt, bsum, RN);
  k_scan_b<<<1, 1024, 0, stream>>>(bsum, bscan, NB, off + RN);
  k_scan_f<<<NB, 256, 0, stream>>>(cnt, bscan, off, RN);
  k_bucket<<<(E + 255) / 256, 256, 0, stream>>>(src, dst, rel, edge_norm, off, fill,
                                                spack, snorm, E, NV);

  // target sort by relation (for fused scoring)
  hipMemsetAsync(tcnt, 0, (size_t)(2 * R + 8) * 4, stream);  // tcnt + tfill
  hipMemsetAsync(sidx, 0, sz_tix, stream);
  hipMemsetAsync(tmap, 0xFF, sz_tix, stream);
  hipMemsetAsync(d_out, 0, (size_t)2 * T * 4, stream);
  k_thist<<<(2 * T + 255) / 256, 256, 0, stream>>>(pos_rel, neg_rel, tcnt, T);
  k_tscan<<<1, 1, 0, stream>>>(tcnt, tpo, btile, R, TB);
  k_tbucket<<<(2 * T + 255) / 256, 256, 0, stream>>>(
      pos_src, pos_rel, pos_dst, neg_src, neg_rel, neg_dst,
      tpo, tfill, sidx, oidx, tmap, T);

  const int MT = Mpad / 256;
  const int KG = RG * D;
  const int gblocks = Mpad / 4;
  for (int l = 0; l < L; ++l) {
    k_gemm_tn<2><<<MT * 3, 512, 0, stream>>>(
        h, wt_self + (size_t)l * D * D, agg, nullptr, NV, D, D, MT, 3);
    for (int gi = 0; gi < NGRP; ++gi) {
      k_gather<<<gblocks, 256, 0, stream>>>(h, off, spack, snorm, Acat, NV,
                                            gi * RG, gi * RG + RG, KG);
      const unsigned short* Bw = wt_rel + (size_t)(l * NGRP + gi) * D * KG;
      if (gi == NGRP - 1)
        k_gemm_tn<1><<<MT * 3, 512, 0, stream>>>(Acat, Bw, h, agg, NV, D, KG, MT, 3);
      else
        k_gemm_tn<3><<<MT * 3, 512, 0, stream>>>(Acat, Bw, agg, agg, NV, D, KG, MT, 3);
    }
  }
  // fused scoring: one batched GEMM over relation-sorted targets
  k_gemm_score<<<TB * 3, 512, 0, stream>>>(h, wt_score, (float*)d_out,
                                           sidx, oidx, tmap, btile, TB, 3);
}

// Round 10
// 889.239 us; speedup vs baseline: 2.3012x; 2.3012x over previous
//
#include <hip/hip_runtime.h>

typedef float f32x4 __attribute__((ext_vector_type(4)));
typedef __bf16 bf16x8 __attribute__((ext_vector_type(8)));
typedef unsigned short u16x8 __attribute__((ext_vector_type(8)));
typedef unsigned short u16x4 __attribute__((ext_vector_type(4)));

static __device__ __forceinline__ unsigned short f2bf(float f) {
  unsigned int x = __builtin_bit_cast(unsigned int, f);
  x += 0x7FFFu + ((x >> 16) & 1u);
  return (unsigned short)(x >> 16);
}
static __device__ __forceinline__ float bf2f(unsigned short h) {
  unsigned int x = ((unsigned int)h) << 16;
  return __builtin_bit_cast(float, x);
}

static __device__ __forceinline__ void gload_lds16(const unsigned short* g,
                                                   unsigned short* l) {
  __builtin_amdgcn_global_load_lds(
      (const __attribute__((address_space(1))) void*)g,
      (__attribute__((address_space(3))) void*)l, 16, 0, 0);
}

// ---------------- f32 -> bf16 elementwise (vectorized) ----------------
__global__ __launch_bounds__(256) void k_f32_to_bf16(
    const float* __restrict__ in, unsigned short* __restrict__ out, int n4) {
  int i = blockIdx.x * 256 + threadIdx.x;
  if (i >= n4) return;
  float4 v = reinterpret_cast<const float4*>(in)[i];
  u16x4 o = {f2bf(v.x), f2bf(v.y), f2bf(v.z), f2bf(v.w)};
  reinterpret_cast<u16x4*>(out)[i] = o;
}

// ------- transpose+convert into grouped B^T layout -------
__global__ __launch_bounds__(256) void k_transpose_w(
    const float* __restrict__ in, unsigned short* __restrict__ out, int RG) {
  __shared__ float tile[32][33];
  const int D = 768;
  int z = blockIdx.z;
  int j = z % RG, grp = z / RG;
  const float* A = in + (size_t)z * D * D;
  const size_t ld = (size_t)RG * D;
  unsigned short* O = out + (size_t)grp * D * ld + (size_t)j * D;
  int nt = blockIdx.x * 32, kt = blockIdx.y * 32;
  int tx = threadIdx.x, ty = threadIdx.y;
#pragma unroll
  for (int i = 0; i < 4; ++i)
    tile[ty + i * 8][tx] = A[(size_t)(kt + ty + i * 8) * D + nt + tx];
  __syncthreads();
#pragma unroll
  for (int i = 0; i < 4; ++i)
    O[(size_t)(nt + ty + i * 8) * ld + kt + tx] = f2bf(tile[tx][ty + i * 8]);
}

// ---------------- edge sort by (rel, dst) ----------------
__global__ __launch_bounds__(256) void k_hist(const int* __restrict__ dst,
                                              const int* __restrict__ rel,
                                              int* __restrict__ cnt, int E, int NV) {
  int e = blockIdx.x * 256 + threadIdx.x;
  if (e < E) atomicAdd(&cnt[rel[e] * NV + dst[e]], 1);
}

__global__ __launch_bounds__(256) void k_part(const int* __restrict__ cnt,
                                              int* __restrict__ bsum, int n) {
  __shared__ int wsums[4];
  int blk = blockIdx.x, tid = threadIdx.x;
  int base = blk * 1024 + tid * 4;
  int s = 0;
#pragma unroll
  for (int j = 0; j < 4; ++j) {
    int i = base + j;
    if (i < n) s += cnt[i];
  }
#pragma unroll
  for (int d = 1; d < 64; d <<= 1) s += __shfl_xor(s, d, 64);
  if ((tid & 63) == 0) wsums[tid >> 6] = s;
  __syncthreads();
  if (tid == 0) bsum[blk] = wsums[0] + wsums[1] + wsums[2] + wsums[3];
}

__global__ __launch_bounds__(1024) void k_scan_b(const int* __restrict__ bsum,
                                                 int* __restrict__ bscan, int nb,
                                                 int* __restrict__ off_total) {
  __shared__ int wpre[16];
  int tid = threadIdx.x, lane = tid & 63, w = tid >> 6;
  int v = (tid < nb) ? bsum[tid] : 0;
  int inc = v;
#pragma unroll
  for (int d = 1; d < 64; d <<= 1) {
    int t = __shfl_up(inc, d, 64);
    if (lane >= d) inc += t;
  }
  if (lane == 63) wpre[w] = inc;
  __syncthreads();
  if (w == 0) {
    int vv = (lane < 16) ? wpre[lane] : 0;
    int p = vv;
#pragma unroll
    for (int d = 1; d < 16; d <<= 1) {
      int t = __shfl_up(p, d, 64);
      if (lane >= d) p += t;
    }
    if (lane < 16) wpre[lane] = p - vv;
  }
  __syncthreads();
  if (tid < nb) bscan[tid] = wpre[w] + inc - v;
  if (tid == 1023) *off_total = wpre[15] + inc;
}

__global__ __launch_bounds__(256) void k_scan_f(const int* __restrict__ cnt,
                                                const int* __restrict__ bscan,
                                                int* __restrict__ off, int n) {
  __shared__ int wpre[4];
  int blk = blockIdx.x, tid = threadIdx.x, lane = tid & 63, w = tid >> 6;
  int base = blk * 1024 + tid * 4;
  int v[4];
  int s = 0;
#pragma unroll
  for (int j = 0; j < 4; ++j) {
    int i = base + j;
    v[j] = (i < n) ? cnt[i] : 0;
    s += v[j];
  }
  int inc = s;
#pragma unroll
  for (int d = 1; d < 64; d <<= 1) {
    int t = __shfl_up(inc, d, 64);
    if (lane >= d) inc += t;
  }
  if (lane == 63) wpre[w] = inc;
  __syncthreads();
  int wb = 0;
  for (int j = 0; j < w; ++j) wb += wpre[j];
  int run = bscan[blk] + wb + (inc - s);
#pragma unroll
  for (int j = 0; j < 4; ++j) {
    int i = base + j;
    if (i < n) off[i] = run;
    run += v[j];
  }
}

__global__ __launch_bounds__(256) void k_bucket(
    const int* __restrict__ src, const int* __restrict__ dst,
    const int* __restrict__ rel, const float* __restrict__ norm,
    const int* __restrict__ off, int* __restrict__ fill,
    int* __restrict__ spack, float* __restrict__ snorm, int E, int NV) {
  int e = blockIdx.x * 256 + threadIdx.x;
  if (e >= E) return;
  int key = rel[e] * NV + dst[e];
  int slot = off[key] + atomicAdd(&fill[key], 1);
  spack[slot] = src[e];
  snorm[slot] = norm[e];
}

// ------- gather-aggregate into K-concat A slices -------
__global__ __launch_bounds__(256) void k_gather(
    const unsigned short* __restrict__ h, const int* __restrict__ off,
    const int* __restrict__ spack, const float* __restrict__ snorm,
    unsigned short* __restrict__ Acat, int NV, int r0, int r1, int ld) {
  int v = (blockIdx.x * 256 + threadIdx.x) >> 6;
  int lane = threadIdx.x & 63;
  int col = lane * 4;
  for (int r = r0; r < r1; ++r) {
    float a[12];
#pragma unroll
    for (int j = 0; j < 12; ++j) a[j] = 0.f;
    if (v < NV) {
      int beg = off[r * NV + v], end = off[r * NV + v + 1];
      for (int p = beg; p < end; ++p) {
        const unsigned short* row = h + (size_t)spack[p] * 768 + col;
        float nm = snorm[p];
#pragma unroll
        for (int c = 0; c < 3; ++c) {
          u16x4 vv = *reinterpret_cast<const u16x4*>(row + c * 256);
#pragma unroll
          for (int j = 0; j < 4; ++j) a[c * 4 + j] += nm * bf2f(vv[j]);
        }
      }
    }
    unsigned short* orow = Acat + (size_t)v * ld + (size_t)(r - r0) * 768 + col;
#pragma unroll
    for (int c = 0; c < 3; ++c) {
      u16x4 o = {f2bf(a[c * 4 + 0]), f2bf(a[c * 4 + 1]),
                 f2bf(a[c * 4 + 2]), f2bf(a[c * 4 + 3])};
      *reinterpret_cast<u16x4*>(orow + c * 256) = o;
    }
  }
}

// ---------------- target sort by relation: contention-free 3 passes ----------
// pass 1: per-block LDS histogram -> bcnt[r][blk]  (no global atomics)
__global__ __launch_bounds__(256) void k_thist2(
    const int* __restrict__ pr, const int* __restrict__ nr,
    int* __restrict__ bcnt, int T, int NBT) {
  __shared__ int lh[8];
  int tid = threadIdx.x, blk = blockIdx.x;
  if (tid < 8) lh[tid] = 0;
  __syncthreads();
  int t = blk * 256 + tid;
  if (t < 2 * T) {
    int r = (t < T) ? pr[t] : nr[t - T];
    atomicAdd(&lh[r], 1);  // LDS, non-returning
  }
  __syncthreads();
  if (tid < 8) bcnt[tid * NBT + blk] = lh[tid];
}

// pass 2: one block, 8 waves; wave r scans its NBT counts -> block bases with
// padded relation offsets tpo; threads fill btile.
__global__ __launch_bounds__(512) void k_tscan2(
    int* __restrict__ bcnt, int* __restrict__ tpo, int* __restrict__ btile,
    int NBT, int TB) {
  __shared__ int totals[8];
  __shared__ int tpo_s[9];
  int tid = threadIdx.x, lane = tid & 63, w = tid >> 6;
  if (w < 8) {
    int carry = 0;
    for (int base = 0; base < NBT; base += 64) {
      int i = base + lane;
      int v = (i < NBT) ? bcnt[w * NBT + i] : 0;
      int s = v;
#pragma unroll
      for (int d = 1; d < 64; d <<= 1) {
        int t2 = __shfl_up(s, d, 64);
        if (lane >= d) s += t2;
      }
      if (i < NBT) bcnt[w * NBT + i] = carry + s - v;  // exclusive prefix
      carry += __shfl(s, 63, 64);
    }
    if (lane == 0) totals[w] = carry;
  }
  __syncthreads();
  if (tid == 0) {
    int run = 0;
    for (int r = 0; r < 8; ++r) {
      tpo_s[r] = run;
      run += (totals[r] + 255) & ~255;
    }
    tpo_s[8] = run;
    for (int r = 0; r <= 8; ++r) tpo[r] = tpo_s[r];
  }
  __syncthreads();
  if (w < 8) {
    for (int base = 0; base < NBT; base += 64) {
      int i = base + lane;
      if (i < NBT) bcnt[w * NBT + i] += tpo_s[w];
    }
  }
  for (int mt = tid; mt < TB; mt += 512) {
    int base = mt * 256;
    int b = -1;
    if (base < tpo_s[8]) {
      for (int r = 0; r < 8; ++r)
        if (base >= tpo_s[r] && base < tpo_s[r + 1]) { b = r; break; }
    }
    btile[mt] = b;
  }
}

// pass 3: per-block local rank via LDS atomics; slot = bcnt[r][blk] + rank
__global__ __launch_bounds__(256) void k_tbucket2(
    const int* __restrict__ ps, const int* __restrict__ pr, const int* __restrict__ pd,
    const int* __restrict__ ns, const int* __restrict__ nr, const int* __restrict__ nd,
    const int* __restrict__ bcnt, int* __restrict__ sidx, int* __restrict__ oidx,
    int* __restrict__ tmap, int T, int NBT) {
  __shared__ int lh[8];
  __shared__ int base_s[8];
  int tid = threadIdx.x, blk = blockIdx.x;
  if (tid < 8) {
    lh[tid] = 0;
    base_s[tid] = bcnt[tid * NBT + blk];
  }
  __syncthreads();
  int t = blk * 256 + tid;
  if (t >= 2 * T) return;
  int s, r, o;
  if (t < T) { s = ps[t]; r = pr[t]; o = pd[t]; }
  else       { s = ns[t - T]; r = nr[t - T]; o = nd[t - T]; }
  int rank = atomicAdd(&lh[r], 1);  // LDS returning (256 ops, 8 banks: ~ns)
  int slot = base_s[r] + rank;
  sidx[slot] = s;
  oidx[slot] = o;
  tmap[slot] = t;
}

// ================= shared GEMM pieces (256x256 tile, BK=64, 8 waves) =========
#define STAGE_A(BUF, HALF, TT)                                                   \
  do {                                                                           \
    const unsigned short* _s =                                                   \
        A + (size_t)(m0 + (HALF) * 128 + srow) * K + (size_t)(TT) * 64 + gcol;   \
    gload_lds16(_s, &As[BUF][HALF][w << 3][0]);                                  \
    gload_lds16(_s + (size_t)64 * K, &As[BUF][HALF][64 + (w << 3)][0]);          \
  } while (0)
#define STAGE_B(BUF, HALF, TT)                                                   \
  do {                                                                           \
    const unsigned short* _s =                                                   \
        B + (size_t)(n0 + (HALF) * 128 + srow) * K + (size_t)(TT) * 64 + gcol;   \
    gload_lds16(_s, &Bs[BUF][HALF][w << 3][0]);                                  \
    gload_lds16(_s + (size_t)64 * K, &Bs[BUF][HALF][64 + (w << 3)][0]);          \
  } while (0)
#define GEMM_PRE()                                                               \
  const int tid = threadIdx.x;                                                   \
  const int lane = tid & 63;                                                     \
  const int w = tid >> 6;                                                        \
  const int wr = w >> 2;                                                         \
  const int wc = w & 3;                                                          \
  const int lr = lane & 15, lg = lane >> 4;                                      \
  int bid = blockIdx.x;                                                          \
  const int per = 8 * NT;                                                        \
  int grp = bid / per, rem = bid % per;                                          \
  int mstart = grp * 8;                                                          \
  int gsz = MT - mstart;                                                         \
  if (gsz > 8) gsz = 8;                                                          \
  const int mt = mstart + rem % gsz;                                             \
  const int ntile = rem / gsz;                                                   \
  const int m0 = mt * 256, n0 = ntile * 256;                                     \
  const int srow = tid >> 3;                                                     \
  const int gcol = (((tid & 7) ^ (tid >> 3)) & 7) * 8;                           \
  const int nk = K >> 6;
#define R_BV6(BUF)                                                               \
  _Pragma("unroll") for (int nb = 0; nb < 2; ++nb)                               \
  _Pragma("unroll") for (int j = 0; j < 2; ++j)                                  \
  _Pragma("unroll") for (int kk = 0; kk < 2; ++kk)                               \
      bv[nb][j][kk] = *reinterpret_cast<const bf16x8*>(                          \
          &Bs[BUF][nb][wc * 32 + j * 16 + lr][((lg + 4 * kk) ^ (lr & 7)) * 8]);
#define R_AF6(BUF, HALF)                                                         \
  _Pragma("unroll") for (int i = 0; i < 4; ++i)                                  \
  _Pragma("unroll") for (int kk = 0; kk < 2; ++kk)                               \
      af[i][kk] = *reinterpret_cast<const bf16x8*>(                              \
          &As[BUF][HALF][wr * 64 + i * 16 + lr][((lg + 4 * kk) ^ (lr & 7)) * 8]);
// r6 2-phase main loop body (STAGEA_MACRO lets the score kernel use indirect A)
#define GEMM_LOOP(STAGEA_MACRO)                                                  \
  bf16x8 af[4][2], bv[2][2][2];                                                  \
  for (int t = 0; t < nk; ++t) {                                                 \
    const int buf = t & 1;                                                       \
    if (t + 1 < nk)                                                              \
      asm volatile("s_waitcnt vmcnt(4)" ::: "memory");                           \
    else                                                                         \
      asm volatile("s_waitcnt vmcnt(0)" ::: "memory");                           \
    __builtin_amdgcn_s_barrier();                                                \
    asm volatile("" ::: "memory");                                               \
    R_AF6(buf, 0);                                                               \
    R_BV6(buf);                                                                  \
    if (t + 1 < nk) {                                                            \
      STAGEA_MACRO(buf ^ 1, 1, t + 1);                                           \
      STAGE_B(buf ^ 1, 0, t + 1);                                                \
    }                                                                            \
    __builtin_amdgcn_s_setprio(1);                                               \
    _Pragma("unroll") for (int i = 0; i < 4; ++i)                                \
    _Pragma("unroll") for (int nb = 0; nb < 2; ++nb)                             \
    _Pragma("unroll") for (int j = 0; j < 2; ++j)                                \
    _Pragma("unroll") for (int kk = 0; kk < 2; ++kk)                             \
        acc[0][nb][i][j] = __builtin_amdgcn_mfma_f32_16x16x32_bf16(              \
            af[i][kk], bv[nb][j][kk], acc[0][nb][i][j], 0, 0, 0);                \
    __builtin_amdgcn_s_setprio(0);                                               \
    asm volatile("" ::: "memory");                                               \
    __builtin_amdgcn_s_barrier();                                                \
    asm volatile("" ::: "memory");                                               \
    R_AF6(buf, 1);                                                               \
    if (t + 2 < nk) {                                                            \
      STAGEA_MACRO(buf, 0, t + 2);                                               \
      STAGE_B(buf, 1, t + 2);                                                    \
    }                                                                            \
    __builtin_amdgcn_s_setprio(1);                                               \
    _Pragma("unroll") for (int i = 0; i < 4; ++i)                                \
    _Pragma("unroll") for (int nb = 0; nb < 2; ++nb)                             \
    _Pragma("unroll") for (int j = 0; j < 2; ++j)                                \
    _Pragma("unroll") for (int kk = 0; kk < 2; ++kk)                             \
        acc[1][nb][i][j] = __builtin_amdgcn_mfma_f32_16x16x32_bf16(              \
            af[i][kk], bv[nb][j][kk], acc[1][nb][i][j], 0, 0, 0);                \
    __builtin_amdgcn_s_setprio(0);                                               \
  }

// ---------------- k_gemm_tn: round-6 2-phase schedule ----------------
template <int EPI>
__global__ __launch_bounds__(512, 2) void k_gemm_tn(
    const unsigned short* __restrict__ A, const unsigned short* __restrict__ B,
    void* __restrict__ Cp, const float* __restrict__ C0,
    int M, int N, int K, int MT, int NT) {
  __shared__ unsigned short As[2][2][128][64];
  __shared__ unsigned short Bs[2][2][128][64];
  GEMM_PRE();
  f32x4 acc[2][2][4][2] = {};

  STAGE_A(0, 0, 0);
  STAGE_B(0, 1, 0);
  STAGE_A(0, 1, 0);
  STAGE_B(0, 0, 0);
  if (nk > 1) {
    STAGE_A(1, 0, 1);
    STAGE_B(1, 1, 1);
  }
  GEMM_LOOP(STAGE_A);

#pragma unroll
  for (int ma = 0; ma < 2; ++ma)
#pragma unroll
    for (int i = 0; i < 4; ++i)
#pragma unroll
      for (int q = 0; q < 4; ++q) {
        int r = m0 + ma * 128 + wr * 64 + i * 16 + lg * 4 + q;
        if (r >= M) continue;
#pragma unroll
        for (int nb = 0; nb < 2; ++nb)
#pragma unroll
          for (int j = 0; j < 2; ++j) {
            int cn = n0 + nb * 128 + wc * 32 + j * 16 + lr;
            float v = acc[ma][nb][i][j][q];
            size_t idx = (size_t)r * N + cn;
            if (EPI == 0) {
              ((unsigned short*)Cp)[idx] = f2bf(v);
            } else if (EPI == 1) {
              v += C0[idx];
              v = v > 0.f ? v : 0.f;
              ((unsigned short*)Cp)[idx] = f2bf(v);
            } else if (EPI == 2) {
              ((float*)Cp)[idx] = v;
            } else {
              ((float*)Cp)[idx] = v + C0[idx];
            }
          }
      }
}

// ---------------- k_gemm_score: indirect-A batched-B GEMM + fused DistMult dot --
#define STAGE_AI(BUF, HALF, TT)                                                  \
  do {                                                                           \
    gload_lds16(pa##HALF##a + (size_t)(TT) * 64, &As[BUF][HALF][w << 3][0]);     \
    gload_lds16(pa##HALF##b + (size_t)(TT) * 64,                                 \
                &As[BUF][HALF][64 + (w << 3)][0]);                               \
  } while (0)

__global__ __launch_bounds__(512, 2) void k_gemm_score(
    const unsigned short* __restrict__ h, const unsigned short* __restrict__ Bw,
    float* __restrict__ out, const int* __restrict__ sidx,
    const int* __restrict__ oidx, const int* __restrict__ tmap,
    const int* __restrict__ btile, int MT, int NT) {
  const int K = 768;
  __shared__ unsigned short As[2][2][128][64];
  __shared__ unsigned short Bs[2][2][128][64];
  GEMM_PRE();
  const int bt = btile[mt];
  if (bt < 0) return;
  const unsigned short* B = Bw + (size_t)bt * K * K;
  const unsigned short* pa0a = h + (size_t)sidx[m0 + srow] * K + gcol;
  const unsigned short* pa0b = h + (size_t)sidx[m0 + 64 + srow] * K + gcol;
  const unsigned short* pa1a = h + (size_t)sidx[m0 + 128 + srow] * K + gcol;
  const unsigned short* pa1b = h + (size_t)sidx[m0 + 192 + srow] * K + gcol;

  f32x4 acc[2][2][4][2] = {};

  STAGE_AI(0, 0, 0);
  STAGE_B(0, 1, 0);
  STAGE_AI(0, 1, 0);
  STAGE_B(0, 0, 0);
  STAGE_AI(1, 0, 1);
  STAGE_B(1, 1, 1);
  GEMM_LOOP(STAGE_AI);

  // fused epilogue: score[t] += dot(row, h[oidx])
#pragma unroll
  for (int ma = 0; ma < 2; ++ma)
#pragma unroll
    for (int i = 0; i < 4; ++i)
#pragma unroll
      for (int q = 0; q < 4; ++q) {
        int slot = m0 + ma * 128 + wr * 64 + i * 16 + lg * 4 + q;
        int t = tmap[slot];
        float p = 0.f;
        if (t >= 0) {
          const unsigned short* orow = h + (size_t)oidx[slot] * K;
#pragma unroll
          for (int nb = 0; nb < 2; ++nb)
#pragma unroll
            for (int j = 0; j < 2; ++j) {
              int cn = n0 + nb * 128 + wc * 32 + j * 16 + lr;
              p += acc[ma][nb][i][j][q] * bf2f(orow[cn]);
            }
        }
#pragma unroll
        for (int d = 1; d < 16; d <<= 1) p += __shfl_xor(p, d, 64);
        if (t >= 0 && lr == 0) unsafeAtomicAdd(&out[t], p);
      }
}

extern "C" void kernel_launch(void* const* d_in, const int* in_sizes, int n_in,
                              void* d_out, int out_size, void* d_ws, size_t ws_size,
                              hipStream_t stream) {
  const float* node_feat = (const float*)d_in[0];
  const float* edge_norm = (const float*)d_in[1];
  const float* W_rel = (const float*)d_in[2];
  const float* W_self = (const float*)d_in[3];
  const float* w_relation = (const float*)d_in[4];
  const int* src = (const int*)d_in[5];
  const int* dst = (const int*)d_in[6];
  const int* rel = (const int*)d_in[7];
  const int* pos_src = (const int*)d_in[8];
  const int* pos_rel = (const int*)d_in[9];
  const int* pos_dst = (const int*)d_in[10];
  const int* neg_src = (const int*)d_in[11];
  const int* neg_rel = (const int*)d_in[12];
  const int* neg_dst = (const int*)d_in[13];

  const int D = 768;
  const int NV = in_sizes[0] / D;
  const int E = in_sizes[1];
  const int L = in_sizes[3] / (D * D);
  const int R = in_sizes[4] / (D * D);
  const int T = in_sizes[8];
  const int Mpad = (NV + 255) & ~255;
  const int RN = R * NV;
  const int NB = (RN + 1023) / 1024;
  const int NBT = (2 * T + 255) / 256;           // target-sort blocks
  const int TB = (2 * T + R * 256 + 255) / 256;  // scoring tile bound
  const int Mbound = TB * 256;

  auto align_up = [](size_t x) { return (x + 255) & ~(size_t)255; };
  size_t sz_wt_rel = align_up((size_t)L * R * D * D * 2);
  size_t sz_wt_self = align_up((size_t)L * D * D * 2);
  size_t sz_wt_score = align_up((size_t)R * D * D * 2);
  size_t sz_h = align_up((size_t)Mpad * D * 2);
  size_t sz_agg = align_up((size_t)Mpad * D * 4);
  size_t sz_cntfill = align_up((size_t)2 * RN * 4);
  size_t sz_off = align_up((size_t)(RN + 8) * 4);
  size_t sz_sp = align_up((size_t)E * 4);
  size_t sz_bs = align_up((size_t)2 * (NB + 8) * 4);
  size_t sz_tix = align_up((size_t)Mbound * 4);
  size_t sz_bcnt = align_up((size_t)8 * NBT * 4);
  size_t sz_tsmall = align_up((size_t)(TB + 64) * 4);
  size_t fixed = sz_wt_rel + sz_wt_self + sz_wt_score + sz_h + sz_agg +
                 sz_cntfill + sz_off + 2 * sz_sp + sz_bs + 3 * sz_tix +
                 sz_bcnt + sz_tsmall;
  int RG = 4;
  while (RG > 1 && fixed + align_up((size_t)Mpad * RG * D * 2) > ws_size) RG >>= 1;
  const int NGRP = R / RG;

  char* wp = (char*)d_ws;
  unsigned short* wt_rel = (unsigned short*)wp; wp += sz_wt_rel;
  unsigned short* wt_self = (unsigned short*)wp; wp += sz_wt_self;
  unsigned short* wt_score = (unsigned short*)wp; wp += sz_wt_score;
  unsigned short* h = (unsigned short*)wp; wp += sz_h;
  float* agg = (float*)wp; wp += sz_agg;
  int* cnt = (int*)wp; int* fill = cnt + RN; wp += sz_cntfill;
  int* off = (int*)wp; wp += sz_off;
  int* spack = (int*)wp; wp += sz_sp;
  float* snorm = (float*)wp; wp += sz_sp;
  int* bsum = (int*)wp; int* bscan = bsum + NB + 4; wp += sz_bs;
  int* sidx = (int*)wp; wp += sz_tix;
  int* oidx = (int*)wp; wp += sz_tix;
  int* tmap = (int*)wp; wp += sz_tix;
  int* bcnt = (int*)wp; wp += sz_bcnt;
  int* btile = (int*)wp;                  // TB ints
  int* tpo = btile + TB + 8;              // R+1
  wp += sz_tsmall;
  unsigned short* Acat = (unsigned short*)wp;

  dim3 tb32(32, 8);
  k_f32_to_bf16<<<(NV * D / 4 + 255) / 256, 256, 0, stream>>>(node_feat, h, NV * D / 4);
  if (Mpad > NV)
    hipMemsetAsync(h + (size_t)NV * D, 0, (size_t)(Mpad - NV) * D * 2, stream);
  k_transpose_w<<<dim3(24, 24, L * R), tb32, 0, stream>>>(W_rel, wt_rel, RG);
  k_transpose_w<<<dim3(24, 24, L), tb32, 0, stream>>>(W_self, wt_self, 1);
  k_transpose_w<<<dim3(24, 24, R), tb32, 0, stream>>>(w_relation, wt_score, 1);

  // edge sort by (rel, dst)
  hipMemsetAsync(cnt, 0, (size_t)2 * RN * 4, stream);
  k_hist<<<(E + 255) / 256, 256, 0, stream>>>(dst, rel, cnt, E, NV);
  k_part<<<NB, 256, 0, stream>>>(cnt, bsum, RN);
  k_scan_b<<<1, 1024, 0, stream>>>(bsum, bscan, NB, off + RN);
  k_scan_f<<<NB, 256, 0, stream>>>(cnt, bscan, off, RN);
  k_bucket<<<(E + 255) / 256, 256, 0, stream>>>(src, dst, rel, edge_norm, off, fill,
                                                spack, snorm, E, NV);

  // target sort by relation (contention-free)
  hipMemsetAsync(sidx, 0, sz_tix, stream);
  hipMemsetAsync(tmap, 0xFF, sz_tix, stream);
  hipMemsetAsync(d_out, 0, (size_t)2 * T * 4, stream);
  k_thist2<<<NBT, 256, 0, stream>>>(pos_rel, neg_rel, bcnt, T, NBT);
  k_tscan2<<<1, 512, 0, stream>>>(bcnt, tpo, btile, NBT, TB);
  k_tbucket2<<<NBT, 256, 0, stream>>>(pos_src, pos_rel, pos_dst,
                                      neg_src, neg_rel, neg_dst,
                                      bcnt, sidx, oidx, tmap, T, NBT);

  const int MT = Mpad / 256;
  const int KG = RG * D;
  const int gblocks = Mpad / 4;
  for (int l = 0; l < L; ++l) {
    k_gemm_tn<2><<<MT * 3, 512, 0, stream>>>(
        h, wt_self + (size_t)l * D * D, agg, nullptr, NV, D, D, MT, 3);
    for (int gi = 0; gi < NGRP; ++gi) {
      k_gather<<<gblocks, 256, 0, stream>>>(h, off, spack, snorm, Acat, NV,
                                            gi * RG, gi * RG + RG, KG);
      const unsigned short* Bw = wt_rel + (size_t)(l * NGRP + gi) * D * KG;
      if (gi == NGRP - 1)
        k_gemm_tn<1><<<MT * 3, 512, 0, stream>>>(Acat, Bw, h, agg, NV, D, KG, MT, 3);
      else
        k_gemm_tn<3><<<MT * 3, 512, 0, stream>>>(Acat, Bw, agg, agg, NV, D, KG, MT, 3);
    }
  }
  // fused scoring: one batched GEMM over relation-sorted targets
  k_gemm_score<<<TB * 3, 512, 0, stream>>>(h, wt_score, (float*)d_out,
                                           sidx, oidx, tmap, btile, TB, 3);
}

// Round 11
// 873.621 us; speedup vs baseline: 2.3423x; 1.0179x over previous
//
#include <hip/hip_runtime.h>

typedef float f32x4 __attribute__((ext_vector_type(4)));
typedef __bf16 bf16x8 __attribute__((ext_vector_type(8)));
typedef unsigned short u16x8 __attribute__((ext_vector_type(8)));
typedef unsigned short u16x4 __attribute__((ext_vector_type(4)));

static __device__ __forceinline__ unsigned short f2bf(float f) {
  unsigned int x = __builtin_bit_cast(unsigned int, f);
  x += 0x7FFFu + ((x >> 16) & 1u);
  return (unsigned short)(x >> 16);
}
static __device__ __forceinline__ float bf2f(unsigned short h) {
  unsigned int x = ((unsigned int)h) << 16;
  return __builtin_bit_cast(float, x);
}

static __device__ __forceinline__ void gload_lds16(const unsigned short* g,
                                                   unsigned short* l) {
  __builtin_amdgcn_global_load_lds(
      (const __attribute__((address_space(1))) void*)g,
      (__attribute__((address_space(3))) void*)l, 16, 0, 0);
}

// ---------------- f32 -> bf16 elementwise (vectorized) ----------------
__global__ __launch_bounds__(256) void k_f32_to_bf16(
    const float* __restrict__ in, unsigned short* __restrict__ out, int n4) {
  int i = blockIdx.x * 256 + threadIdx.x;
  if (i >= n4) return;
  float4 v = reinterpret_cast<const float4*>(in)[i];
  u16x4 o = {f2bf(v.x), f2bf(v.y), f2bf(v.z), f2bf(v.w)};
  reinterpret_cast<u16x4*>(out)[i] = o;
}

// ------- transpose+convert into grouped B^T layout -------
// matrix z -> slice j0 + z%G of out-matrix z/G; out row length SL*768.
__global__ __launch_bounds__(256) void k_transpose_w(
    const float* __restrict__ in, unsigned short* __restrict__ out,
    int G, int SL, int j0) {
  __shared__ float tile[32][33];
  const int D = 768;
  int z = blockIdx.z;
  int j = j0 + z % G, grp = z / G;
  const float* A = in + (size_t)z * D * D;
  const size_t ld = (size_t)SL * D;
  unsigned short* O = out + (size_t)grp * D * ld + (size_t)j * D;
  int nt = blockIdx.x * 32, kt = blockIdx.y * 32;
  int tx = threadIdx.x, ty = threadIdx.y;
#pragma unroll
  for (int i = 0; i < 4; ++i)
    tile[ty + i * 8][tx] = A[(size_t)(kt + ty + i * 8) * D + nt + tx];
  __syncthreads();
#pragma unroll
  for (int i = 0; i < 4; ++i)
    O[(size_t)(nt + ty + i * 8) * ld + kt + tx] = f2bf(tile[tx][ty + i * 8]);
}

// ---------------- keyed counting sort (shared by edges and targets) ----------
__global__ __launch_bounds__(256) void k_hist(const int* __restrict__ dst,
                                              const int* __restrict__ rel,
                                              int* __restrict__ cnt, int E, int NV) {
  int e = blockIdx.x * 256 + threadIdx.x;
  if (e < E) atomicAdd(&cnt[rel[e] * NV + dst[e]], 1);
}

__global__ __launch_bounds__(256) void k_hist_t(
    const int* __restrict__ ps, const int* __restrict__ pr,
    const int* __restrict__ ns, const int* __restrict__ nr,
    int* __restrict__ cnt, int T, int NV) {
  int t = blockIdx.x * 256 + threadIdx.x;
  if (t >= 2 * T) return;
  int s = (t < T) ? ps[t] : ns[t - T];
  int r = (t < T) ? pr[t] : nr[t - T];
  atomicAdd(&cnt[r * NV + s], 1);
}

__global__ __launch_bounds__(256) void k_part(const int* __restrict__ cnt,
                                              int* __restrict__ bsum, int n) {
  __shared__ int wsums[4];
  int blk = blockIdx.x, tid = threadIdx.x;
  int base = blk * 1024 + tid * 4;
  int s = 0;
#pragma unroll
  for (int j = 0; j < 4; ++j) {
    int i = base + j;
    if (i < n) s += cnt[i];
  }
#pragma unroll
  for (int d = 1; d < 64; d <<= 1) s += __shfl_xor(s, d, 64);
  if ((tid & 63) == 0) wsums[tid >> 6] = s;
  __syncthreads();
  if (tid == 0) bsum[blk] = wsums[0] + wsums[1] + wsums[2] + wsums[3];
}

__global__ __launch_bounds__(1024) void k_scan_b(const int* __restrict__ bsum,
                                                 int* __restrict__ bscan, int nb,
                                                 int* __restrict__ off_total) {
  __shared__ int wpre[16];
  int tid = threadIdx.x, lane = tid & 63, w = tid >> 6;
  int v = (tid < nb) ? bsum[tid] : 0;
  int inc = v;
#pragma unroll
  for (int d = 1; d < 64; d <<= 1) {
    int t = __shfl_up(inc, d, 64);
    if (lane >= d) inc += t;
  }
  if (lane == 63) wpre[w] = inc;
  __syncthreads();
  if (w == 0) {
    int vv = (lane < 16) ? wpre[lane] : 0;
    int p = vv;
#pragma unroll
    for (int d = 1; d < 16; d <<= 1) {
      int t = __shfl_up(p, d, 64);
      if (lane >= d) p += t;
    }
    if (lane < 16) wpre[lane] = p - vv;
  }
  __syncthreads();
  if (tid < nb) bscan[tid] = wpre[w] + inc - v;
  if (tid == 1023) *off_total = wpre[15] + inc;
}

__global__ __launch_bounds__(256) void k_scan_f(const int* __restrict__ cnt,
                                                const int* __restrict__ bscan,
                                                int* __restrict__ off, int n) {
  __shared__ int wpre[4];
  int blk = blockIdx.x, tid = threadIdx.x, lane = tid & 63, w = tid >> 6;
  int base = blk * 1024 + tid * 4;
  int v[4];
  int s = 0;
#pragma unroll
  for (int j = 0; j < 4; ++j) {
    int i = base + j;
    v[j] = (i < n) ? cnt[i] : 0;
    s += v[j];
  }
  int inc = s;
#pragma unroll
  for (int d = 1; d < 64; d <<= 1) {
    int t = __shfl_up(inc, d, 64);
    if (lane >= d) inc += t;
  }
  if (lane == 63) wpre[w] = inc;
  __syncthreads();
  int wb = 0;
  for (int j = 0; j < w; ++j) wb += wpre[j];
  int run = bscan[blk] + wb + (inc - s);
#pragma unroll
  for (int j = 0; j < 4; ++j) {
    int i = base + j;
    if (i < n) off[i] = run;
    run += v[j];
  }
}

__global__ __launch_bounds__(256) void k_bucket(
    const int* __restrict__ src, const int* __restrict__ dst,
    const int* __restrict__ rel, const float* __restrict__ norm,
    const int* __restrict__ off, int* __restrict__ fill,
    int* __restrict__ spack, float* __restrict__ snorm, int E, int NV) {
  int e = blockIdx.x * 256 + threadIdx.x;
  if (e >= E) return;
  int key = rel[e] * NV + dst[e];
  int slot = off[key] + atomicAdd(&fill[key], 1);
  spack[slot] = src[e];
  snorm[slot] = norm[e];
}

// padded per-relation bases + per-tile relation map from (r,s)-sorted offsets
__global__ __launch_bounds__(512) void k_tprep(
    const int* __restrict__ off2, int* __restrict__ tpo, int* __restrict__ rbase,
    int* __restrict__ btile, int NV, int R, int TB) {
  __shared__ int tpo_s[17];
  int tid = threadIdx.x;
  if (tid == 0) {
    int run = 0;
    for (int r = 0; r < R; ++r) {
      rbase[r] = off2[r * NV];
      int tot = off2[(r + 1) * NV] - off2[r * NV];
      tpo_s[r] = run;
      run += (tot + 255) & ~255;
    }
    tpo_s[R] = run;
    for (int r = 0; r <= R; ++r) tpo[r] = tpo_s[r];
  }
  __syncthreads();
  for (int mt = tid; mt < TB; mt += 512) {
    int base = mt * 256;
    int b = -1;
    if (base < tpo_s[R]) {
      for (int r = 0; r < R; ++r)
        if (base >= tpo_s[r] && base < tpo_s[r + 1]) { b = r; break; }
    }
    btile[mt] = b;
  }
}

__global__ __launch_bounds__(256) void k_tbucket3(
    const int* __restrict__ ps, const int* __restrict__ pr, const int* __restrict__ pd,
    const int* __restrict__ ns, const int* __restrict__ nr, const int* __restrict__ nd,
    const int* __restrict__ off2, int* __restrict__ fill,
    const int* __restrict__ tpo, const int* __restrict__ rbase,
    int* __restrict__ sidx, int* __restrict__ oidx, int* __restrict__ tmap,
    int T, int NV) {
  int t = blockIdx.x * 256 + threadIdx.x;
  if (t >= 2 * T) return;
  int s, r, o;
  if (t < T) { s = ps[t]; r = pr[t]; o = pd[t]; }
  else       { s = ns[t - T]; r = nr[t - T]; o = nd[t - T]; }
  int key = r * NV + s;
  int rank = atomicAdd(&fill[key], 1);
  int slot = tpo[r] + (off2[key] - rbase[r]) + rank;
  sidx[slot] = s;
  oidx[slot] = o;
  tmap[slot] = t;
}

// ------- gather-aggregate into K-concat A slices -------
__global__ __launch_bounds__(256) void k_gather(
    const unsigned short* __restrict__ h, const int* __restrict__ off,
    const int* __restrict__ spack, const float* __restrict__ snorm,
    unsigned short* __restrict__ Acat, int NV, int r0, int r1, int ld) {
  int v = (blockIdx.x * 256 + threadIdx.x) >> 6;
  int lane = threadIdx.x & 63;
  int col = lane * 4;
  for (int r = r0; r < r1; ++r) {
    float a[12];
#pragma unroll
    for (int j = 0; j < 12; ++j) a[j] = 0.f;
    if (v < NV) {
      int beg = off[r * NV + v], end = off[r * NV + v + 1];
      for (int p = beg; p < end; ++p) {
        const unsigned short* row = h + (size_t)spack[p] * 768 + col;
        float nm = snorm[p];
#pragma unroll
        for (int c = 0; c < 3; ++c) {
          u16x4 vv = *reinterpret_cast<const u16x4*>(row + c * 256);
#pragma unroll
          for (int j = 0; j < 4; ++j) a[c * 4 + j] += nm * bf2f(vv[j]);
        }
      }
    }
    unsigned short* orow = Acat + (size_t)v * ld + (size_t)(r - r0) * 768 + col;
#pragma unroll
    for (int c = 0; c < 3; ++c) {
      u16x4 o = {f2bf(a[c * 4 + 0]), f2bf(a[c * 4 + 1]),
                 f2bf(a[c * 4 + 2]), f2bf(a[c * 4 + 3])};
      *reinterpret_cast<u16x4*>(orow + c * 256) = o;
    }
  }
}

// ================= shared GEMM pieces (256x256 tile, BK=64, 8 waves) =========
#define STAGE_A(BUF, HALF, TT)                                                   \
  do {                                                                           \
    const unsigned short* _s =                                                   \
        A + (size_t)(m0 + (HALF) * 128 + srow) * K + (size_t)(TT) * 64 + gcol;   \
    gload_lds16(_s, &As[BUF][HALF][w << 3][0]);                                  \
    gload_lds16(_s + (size_t)64 * K, &As[BUF][HALF][64 + (w << 3)][0]);          \
  } while (0)
#define STAGE_B(BUF, HALF, TT)                                                   \
  do {                                                                           \
    const unsigned short* _s =                                                   \
        B + (size_t)(n0 + (HALF) * 128 + srow) * K + (size_t)(TT) * 64 + gcol;   \
    gload_lds16(_s, &Bs[BUF][HALF][w << 3][0]);                                  \
    gload_lds16(_s + (size_t)64 * K, &Bs[BUF][HALF][64 + (w << 3)][0]);          \
  } while (0)
#define GEMM_PRE()                                                               \
  const int tid = threadIdx.x;                                                   \
  const int lane = tid & 63;                                                     \
  const int w = tid >> 6;                                                        \
  const int wr = w >> 2;                                                         \
  const int wc = w & 3;                                                          \
  const int lr = lane & 15, lg = lane >> 4;                                      \
  int bid = blockIdx.x;                                                          \
  const int per = 8 * NT;                                                        \
  int grp = bid / per, rem = bid % per;                                          \
  int mstart = grp * 8;                                                          \
  int gsz = MT - mstart;                                                         \
  if (gsz > 8) gsz = 8;                                                          \
  const int mt = mstart + rem % gsz;                                             \
  const int ntile = rem / gsz;                                                   \
  const int m0 = mt * 256, n0 = ntile * 256;                                     \
  const int srow = tid >> 3;                                                     \
  const int gcol = (((tid & 7) ^ (tid >> 3)) & 7) * 8;                           \
  const int nk = K >> 6;
#define R_BV6(BUF)                                                               \
  _Pragma("unroll") for (int nb = 0; nb < 2; ++nb)                               \
  _Pragma("unroll") for (int j = 0; j < 2; ++j)                                  \
  _Pragma("unroll") for (int kk = 0; kk < 2; ++kk)                               \
      bv[nb][j][kk] = *reinterpret_cast<const bf16x8*>(                          \
          &Bs[BUF][nb][wc * 32 + j * 16 + lr][((lg + 4 * kk) ^ (lr & 7)) * 8]);
#define R_AF6(BUF, HALF)                                                         \
  _Pragma("unroll") for (int i = 0; i < 4; ++i)                                  \
  _Pragma("unroll") for (int kk = 0; kk < 2; ++kk)                               \
      af[i][kk] = *reinterpret_cast<const bf16x8*>(                              \
          &As[BUF][HALF][wr * 64 + i * 16 + lr][((lg + 4 * kk) ^ (lr & 7)) * 8]);
#define GEMM_LOOP(STAGEA_MACRO)                                                  \
  bf16x8 af[4][2], bv[2][2][2];                                                  \
  for (int t = 0; t < nk; ++t) {                                                 \
    const int buf = t & 1;                                                       \
    if (t + 1 < nk)                                                              \
      asm volatile("s_waitcnt vmcnt(4)" ::: "memory");                           \
    else                                                                         \
      asm volatile("s_waitcnt vmcnt(0)" ::: "memory");                           \
    __builtin_amdgcn_s_barrier();                                                \
    asm volatile("" ::: "memory");                                               \
    R_AF6(buf, 0);                                                               \
    R_BV6(buf);                                                                  \
    if (t + 1 < nk) {                                                            \
      STAGEA_MACRO(buf ^ 1, 1, t + 1);                                           \
      STAGE_B(buf ^ 1, 0, t + 1);                                                \
    }                                                                            \
    __builtin_amdgcn_s_setprio(1);                                               \
    _Pragma("unroll") for (int i = 0; i < 4; ++i)                                \
    _Pragma("unroll") for (int nb = 0; nb < 2; ++nb)                             \
    _Pragma("unroll") for (int j = 0; j < 2; ++j)                                \
    _Pragma("unroll") for (int kk = 0; kk < 2; ++kk)                             \
        acc[0][nb][i][j] = __builtin_amdgcn_mfma_f32_16x16x32_bf16(              \
            af[i][kk], bv[nb][j][kk], acc[0][nb][i][j], 0, 0, 0);                \
    __builtin_amdgcn_s_setprio(0);                                               \
    asm volatile("" ::: "memory");                                               \
    __builtin_amdgcn_s_barrier();                                                \
    asm volatile("" ::: "memory");                                               \
    R_AF6(buf, 1);                                                               \
    if (t + 2 < nk) {                                                            \
      STAGEA_MACRO(buf, 0, t + 2);                                               \
      STAGE_B(buf, 1, t + 2);                                                    \
    }                                                                            \
    __builtin_amdgcn_s_setprio(1);                                               \
    _Pragma("unroll") for (int i = 0; i < 4; ++i)                                \
    _Pragma("unroll") for (int nb = 0; nb < 2; ++nb)                             \
    _Pragma("unroll") for (int j = 0; j < 2; ++j)                                \
    _Pragma("unroll") for (int kk = 0; kk < 2; ++kk)                             \
        acc[1][nb][i][j] = __builtin_amdgcn_mfma_f32_16x16x32_bf16(              \
            af[i][kk], bv[nb][j][kk], acc[1][nb][i][j], 0, 0, 0);                \
    __builtin_amdgcn_s_setprio(0);                                               \
  }

// ---------------- k_gemm_tn: round-6 2-phase schedule ----------------
// EPI: 1 = bf16 relu(acc + C0_f32); 3 = f32 acc + C0.
template <int EPI>
__global__ __launch_bounds__(512, 2) void k_gemm_tn(
    const unsigned short* __restrict__ A, const unsigned short* __restrict__ B,
    void* __restrict__ Cp, const float* __restrict__ C0,
    int M, int N, int K, int MT, int NT) {
  __shared__ unsigned short As[2][2][128][64];
  __shared__ unsigned short Bs[2][2][128][64];
  GEMM_PRE();
  f32x4 acc[2][2][4][2] = {};

  STAGE_A(0, 0, 0);
  STAGE_B(0, 1, 0);
  STAGE_A(0, 1, 0);
  STAGE_B(0, 0, 0);
  if (nk > 1) {
    STAGE_A(1, 0, 1);
    STAGE_B(1, 1, 1);
  }
  GEMM_LOOP(STAGE_A);

#pragma unroll
  for (int ma = 0; ma < 2; ++ma)
#pragma unroll
    for (int i = 0; i < 4; ++i)
#pragma unroll
      for (int q = 0; q < 4; ++q) {
        int r = m0 + ma * 128 + wr * 64 + i * 16 + lg * 4 + q;
        if (r >= M) continue;
#pragma unroll
        for (int nb = 0; nb < 2; ++nb)
#pragma unroll
          for (int j = 0; j < 2; ++j) {
            int cn = n0 + nb * 128 + wc * 32 + j * 16 + lr;
            float v = acc[ma][nb][i][j][q];
            size_t idx = (size_t)r * N + cn;
            if (EPI == 1) {
              v += C0[idx];
              v = v > 0.f ? v : 0.f;
              ((unsigned short*)Cp)[idx] = f2bf(v);
            } else {
              ((float*)Cp)[idx] = v + C0[idx];
            }
          }
      }
}

// ---------------- k_gemm_fuse: [Acat | h] @ [W_rels | W_self] -> agg (f32) -----
// Two-pointer A: K-slices [0,KA) from Acat (stride KA), [KA,K) from h (stride 768).
#define STAGE_AH(BUF, HALF, TT)                                                  \
  do {                                                                           \
    const unsigned short* _sa =                                                  \
        ((TT) < nkA) ? paA##HALF##a + (size_t)(TT) * 64                          \
                     : paH##HALF##a + (size_t)((TT)-nkA) * 64;                   \
    gload_lds16(_sa, &As[BUF][HALF][w << 3][0]);                                 \
    const unsigned short* _sb =                                                  \
        ((TT) < nkA) ? paA##HALF##b + (size_t)(TT) * 64                          \
                     : paH##HALF##b + (size_t)((TT)-nkA) * 64;                   \
    gload_lds16(_sb, &As[BUF][HALF][64 + (w << 3)][0]);                          \
  } while (0)

__global__ __launch_bounds__(512, 2) void k_gemm_fuse(
    const unsigned short* __restrict__ Ac, const unsigned short* __restrict__ hA,
    const unsigned short* __restrict__ B, float* __restrict__ Cp,
    int M, int N, int K, int KA, int MT, int NT) {
  __shared__ unsigned short As[2][2][128][64];
  __shared__ unsigned short Bs[2][2][128][64];
  GEMM_PRE();
  const int nkA = KA >> 6;
  const unsigned short* paA0a = Ac + (size_t)(m0 + srow) * KA + gcol;
  const unsigned short* paA0b = Ac + (size_t)(m0 + 64 + srow) * KA + gcol;
  const unsigned short* paA1a = Ac + (size_t)(m0 + 128 + srow) * KA + gcol;
  const unsigned short* paA1b = Ac + (size_t)(m0 + 192 + srow) * KA + gcol;
  const unsigned short* paH0a = hA + (size_t)(m0 + srow) * 768 + gcol;
  const unsigned short* paH0b = hA + (size_t)(m0 + 64 + srow) * 768 + gcol;
  const unsigned short* paH1a = hA + (size_t)(m0 + 128 + srow) * 768 + gcol;
  const unsigned short* paH1b = hA + (size_t)(m0 + 192 + srow) * 768 + gcol;

  f32x4 acc[2][2][4][2] = {};

  STAGE_AH(0, 0, 0);
  STAGE_B(0, 1, 0);
  STAGE_AH(0, 1, 0);
  STAGE_B(0, 0, 0);
  if (nk > 1) {
    STAGE_AH(1, 0, 1);
    STAGE_B(1, 1, 1);
  }
  GEMM_LOOP(STAGE_AH);

#pragma unroll
  for (int ma = 0; ma < 2; ++ma)
#pragma unroll
    for (int i = 0; i < 4; ++i)
#pragma unroll
      for (int q = 0; q < 4; ++q) {
        int r = m0 + ma * 128 + wr * 64 + i * 16 + lg * 4 + q;
        if (r >= M) continue;
#pragma unroll
        for (int nb = 0; nb < 2; ++nb)
#pragma unroll
          for (int j = 0; j < 2; ++j) {
            int cn = n0 + nb * 128 + wc * 32 + j * 16 + lr;
            Cp[(size_t)r * N + cn] = acc[ma][nb][i][j][q];
          }
      }
}

// ---------------- k_gemm_score: indirect-A batched-B GEMM + fused DistMult dot --
#define STAGE_AI(BUF, HALF, TT)                                                  \
  do {                                                                           \
    gload_lds16(pa##HALF##a + (size_t)(TT) * 64, &As[BUF][HALF][w << 3][0]);     \
    gload_lds16(pa##HALF##b + (size_t)(TT) * 64,                                 \
                &As[BUF][HALF][64 + (w << 3)][0]);                               \
  } while (0)

__global__ __launch_bounds__(512, 2) void k_gemm_score(
    const unsigned short* __restrict__ h, const unsigned short* __restrict__ Bw,
    float* __restrict__ out, const int* __restrict__ sidx,
    const int* __restrict__ oidx, const int* __restrict__ tmap,
    const int* __restrict__ btile, int MT, int NT) {
  const int K = 768;
  __shared__ unsigned short As[2][2][128][64];
  __shared__ unsigned short Bs[2][2][128][64];
  GEMM_PRE();
  const int bt = btile[mt];
  if (bt < 0) return;
  const unsigned short* B = Bw + (size_t)bt * K * K;
  const unsigned short* pa0a = h + (size_t)sidx[m0 + srow] * K + gcol;
  const unsigned short* pa0b = h + (size_t)sidx[m0 + 64 + srow] * K + gcol;
  const unsigned short* pa1a = h + (size_t)sidx[m0 + 128 + srow] * K + gcol;
  const unsigned short* pa1b = h + (size_t)sidx[m0 + 192 + srow] * K + gcol;

  f32x4 acc[2][2][4][2] = {};

  STAGE_AI(0, 0, 0);
  STAGE_B(0, 1, 0);
  STAGE_AI(0, 1, 0);
  STAGE_B(0, 0, 0);
  STAGE_AI(1, 0, 1);
  STAGE_B(1, 1, 1);
  GEMM_LOOP(STAGE_AI);

  // fused epilogue: score[t] += dot(row, h[oidx])
#pragma unroll
  for (int ma = 0; ma < 2; ++ma)
#pragma unroll
    for (int i = 0; i < 4; ++i)
#pragma unroll
      for (int q = 0; q < 4; ++q) {
        int slot = m0 + ma * 128 + wr * 64 + i * 16 + lg * 4 + q;
        int t = tmap[slot];
        float p = 0.f;
        if (t >= 0) {
          const unsigned short* orow = h + (size_t)oidx[slot] * K;
#pragma unroll
          for (int nb = 0; nb < 2; ++nb)
#pragma unroll
            for (int j = 0; j < 2; ++j) {
              int cn = n0 + nb * 128 + wc * 32 + j * 16 + lr;
              p += acc[ma][nb][i][j][q] * bf2f(orow[cn]);
            }
        }
#pragma unroll
        for (int d = 1; d < 16; d <<= 1) p += __shfl_xor(p, d, 64);
        if (t >= 0 && lr == 0) unsafeAtomicAdd(&out[t], p);
      }
}

extern "C" void kernel_launch(void* const* d_in, const int* in_sizes, int n_in,
                              void* d_out, int out_size, void* d_ws, size_t ws_size,
                              hipStream_t stream) {
  const float* node_feat = (const float*)d_in[0];
  const float* edge_norm = (const float*)d_in[1];
  const float* W_rel = (const float*)d_in[2];
  const float* W_self = (const float*)d_in[3];
  const float* w_relation = (const float*)d_in[4];
  const int* src = (const int*)d_in[5];
  const int* dst = (const int*)d_in[6];
  const int* rel = (const int*)d_in[7];
  const int* pos_src = (const int*)d_in[8];
  const int* pos_rel = (const int*)d_in[9];
  const int* pos_dst = (const int*)d_in[10];
  const int* neg_src = (const int*)d_in[11];
  const int* neg_rel = (const int*)d_in[12];
  const int* neg_dst = (const int*)d_in[13];

  const int D = 768;
  const int NV = in_sizes[0] / D;
  const int E = in_sizes[1];
  const int L = in_sizes[3] / (D * D);
  const int R = in_sizes[4] / (D * D);
  const int T = in_sizes[8];
  const int Mpad = (NV + 255) & ~255;
  const int RN = R * NV;
  const int NB = (RN + 1023) / 1024;
  const int TB = (2 * T + R * 256 + 255) / 256;
  const int Mbound = TB * 256;

  auto align_up = [](size_t x) { return (x + 255) & ~(size_t)255; };
  size_t sz_wt_rel = align_up((size_t)L * (R + 1) * D * D * 2);  // incl. W_self slices
  size_t sz_wt_score = align_up((size_t)R * D * D * 2);
  size_t sz_h = align_up((size_t)Mpad * D * 2);
  size_t sz_agg = align_up((size_t)Mpad * D * 4);
  size_t sz_cntfill = align_up((size_t)2 * RN * 4);
  size_t sz_off = align_up((size_t)(RN + 8) * 4);
  size_t sz_sp = align_up((size_t)E * 4);
  size_t sz_bs = align_up((size_t)2 * (NB + 8) * 4);
  size_t sz_tix = align_up((size_t)Mbound * 4);
  size_t sz_tsmall = align_up((size_t)(TB + 64) * 4);
  size_t fixed = sz_wt_rel + sz_wt_score + sz_h + sz_agg + sz_cntfill +
                 2 * sz_off + 2 * sz_sp + sz_bs + 3 * sz_tix + sz_tsmall;
  int RG = 4;
  while (RG > 1 && fixed + align_up((size_t)Mpad * RG * D * 2) > ws_size) RG >>= 1;
  const int NGRP = R / RG;
  const size_t LW = (size_t)(R + 1) * D * D;  // per-layer weight elems

  char* wp = (char*)d_ws;
  unsigned short* wt_rel = (unsigned short*)wp; wp += sz_wt_rel;
  unsigned short* wt_score = (unsigned short*)wp; wp += sz_wt_score;
  unsigned short* h = (unsigned short*)wp; wp += sz_h;
  float* agg = (float*)wp; wp += sz_agg;
  int* cnt = (int*)wp; int* fill = cnt + RN; wp += sz_cntfill;
  int* off = (int*)wp; wp += sz_off;
  int* off2 = (int*)wp; wp += sz_off;
  int* spack = (int*)wp; wp += sz_sp;
  float* snorm = (float*)wp; wp += sz_sp;
  int* bsum = (int*)wp; int* bscan = bsum + NB + 4; wp += sz_bs;
  int* sidx = (int*)wp; wp += sz_tix;
  int* oidx = (int*)wp; wp += sz_tix;
  int* tmap = (int*)wp; wp += sz_tix;
  int* btile = (int*)wp;            // TB
  int* tpo = btile + TB + 8;        // R+1
  int* rbase = tpo + R + 2;         // R
  wp += sz_tsmall;
  unsigned short* Acat = (unsigned short*)wp;

  dim3 tb32(32, 8);
  k_f32_to_bf16<<<(NV * D / 4 + 255) / 256, 256, 0, stream>>>(node_feat, h, NV * D / 4);
  if (Mpad > NV)
    hipMemsetAsync(h + (size_t)NV * D, 0, (size_t)(Mpad - NV) * D * 2, stream);
  // weights: group 0 of each layer gets RG rel slices + W_self at slice RG
  for (int l = 0; l < L; ++l) {
    k_transpose_w<<<dim3(24, 24, RG), tb32, 0, stream>>>(
        W_rel + (size_t)l * R * D * D, wt_rel + (size_t)l * LW, RG, RG + 1, 0);
    k_transpose_w<<<dim3(24, 24, 1), tb32, 0, stream>>>(
        W_self + (size_t)l * D * D, wt_rel + (size_t)l * LW, 1, RG + 1, RG);
    for (int gi = 1; gi < NGRP; ++gi)
      k_transpose_w<<<dim3(24, 24, RG), tb32, 0, stream>>>(
          W_rel + (size_t)(l * R + gi * RG) * D * D,
          wt_rel + (size_t)l * LW + (size_t)(RG + 1) * D * D +
              (size_t)(gi - 1) * RG * D * D, RG, RG, 0);
  }
  k_transpose_w<<<dim3(24, 24, R), tb32, 0, stream>>>(w_relation, wt_score, 1, 1, 0);

  // edge sort by (rel, dst)
  hipMemsetAsync(cnt, 0, (size_t)2 * RN * 4, stream);
  k_hist<<<(E + 255) / 256, 256, 0, stream>>>(dst, rel, cnt, E, NV);
  k_part<<<NB, 256, 0, stream>>>(cnt, bsum, RN);
  k_scan_b<<<1, 1024, 0, stream>>>(bsum, bscan, NB, off + RN);
  k_scan_f<<<NB, 256, 0, stream>>>(cnt, bscan, off, RN);
  k_bucket<<<(E + 255) / 256, 256, 0, stream>>>(src, dst, rel, edge_norm, off, fill,
                                                spack, snorm, E, NV);

  // target sort by (rel, src) — reuses cnt/fill/bsum/bscan (dead after edge sort)
  hipMemsetAsync(cnt, 0, (size_t)2 * RN * 4, stream);
  k_hist_t<<<(2 * T + 255) / 256, 256, 0, stream>>>(pos_src, pos_rel,
                                                    neg_src, neg_rel, cnt, T, NV);
  k_part<<<NB, 256, 0, stream>>>(cnt, bsum, RN);
  k_scan_b<<<1, 1024, 0, stream>>>(bsum, bscan, NB, off2 + RN);
  k_scan_f<<<NB, 256, 0, stream>>>(cnt, bscan, off2, RN);
  k_tprep<<<1, 512, 0, stream>>>(off2, tpo, rbase, btile, NV, R, TB);
  hipMemsetAsync(sidx, 0, sz_tix, stream);
  hipMemsetAsync(tmap, 0xFF, sz_tix, stream);
  hipMemsetAsync(d_out, 0, (size_t)2 * T * 4, stream);
  k_tbucket3<<<(2 * T + 255) / 256, 256, 0, stream>>>(
      pos_src, pos_rel, pos_dst, neg_src, neg_rel, neg_dst,
      off2, fill, tpo, rbase, sidx, oidx, tmap, T, NV);

  const int MT = Mpad / 256;
  const int KG = RG * D;
  const int gblocks = Mpad / 4;
  for (int l = 0; l < L; ++l) {
    // group 0 (fused with self-loop): agg = [A_0..A_{RG-1} | h] @ [W.. | W_self]
    k_gather<<<gblocks, 256, 0, stream>>>(h, off, spack, snorm, Acat, NV, 0, RG, KG);
    k_gemm_fuse<<<MT * 3, 512, 0, stream>>>(
        Acat, h, wt_rel + (size_t)l * LW, agg, NV, D, KG + D, KG, MT, 3);
    for (int gi = 1; gi < NGRP; ++gi) {
      k_gather<<<gblocks, 256, 0, stream>>>(h, off, spack, snorm, Acat, NV,
                                            gi * RG, gi * RG + RG, KG);
      const unsigned short* Bw = wt_rel + (size_t)l * LW +
                                 (size_t)(RG + 1) * D * D +
                                 (size_t)(gi - 1) * RG * D * D;
      if (gi == NGRP - 1)  // last: h = relu(acc + agg), in place (reads Acat only)
        k_gemm_tn<1><<<MT * 3, 512, 0, stream>>>(Acat, Bw, h, agg, NV, D, KG, MT, 3);
      else
        k_gemm_tn<3><<<MT * 3, 512, 0, stream>>>(Acat, Bw, agg, agg, NV, D, KG, MT, 3);
    }
  }
  // fused scoring over (rel,src)-sorted targets
  k_gemm_score<<<TB * 3, 512, 0, stream>>>(h, wt_score, (float*)d_out,
                                           sidx, oidx, tmap, btile, TB, 3);
}